// Round 6
// baseline (422.536 us; speedup 1.0000x reference)
//
#include <hip/hip_runtime.h>
#include <hip/hip_fp16.h>
#include <math.h>

// B=32, S=1, DIM=2048, NH=32, NKV=8, HD=64, L=2048, START_POS=2047.
// Inputs float32. OUTPUT float32.
#define NQKV 3072
#define NS   32     // flash splits per batch (block level)
#define SPL  64     // positions per block split
#define PW   16     // positions per w2 wave-group (SPL/4)

__device__ __forceinline__ int read_sp(const int* spp) {
  if (!spp) return 2047;
  int raw = spp[0];
  if (raw >= 0 && raw < 2048) return raw;
  union { int i; float f; } u; u.i = raw;
  if (u.f >= 0.f && u.f < 2048.f) return (int)u.f;
  return 2047;
}

// ---------------- K0: transpose x -> xt[2048][32], zero qkvacc + out,
//                  block 0 computes RoPE cos/sin table (f64 angles)
__global__ __launch_bounds__(256) void k_prep6(const float* __restrict__ x,
                                               float* __restrict__ xt,
                                               float* __restrict__ qkvacc,
                                               float* __restrict__ out,
                                               float* __restrict__ rope,
                                               const int* __restrict__ spp) {
  int idx = blockIdx.x * 256 + threadIdx.x;   // 65536 total
  int r = idx >> 11, k = idx & 2047;
  xt[k * 32 + r] = x[idx];
  out[idx] = 0.f;                              // 65536 = 32*2048
  for (int z = idx; z < 32 * NQKV; z += 65536) qkvacc[z] = 0.f;
  if (blockIdx.x == 0 && threadIdx.x < 32) {
    int i = threadIdx.x;
    int sp = read_sp(spp);
    double freq = pow(10000.0, -(double)(2 * i) / 64.0);
    double ang = (double)sp * freq;
    double sd, cd; sincos(ang, &sd, &cd);
    rope[2 * i]     = (float)cd;
    rope[2 * i + 1] = (float)sd;
  }
}

// ---------------- K1: QKV GEMM, 1 col/thread, k-split via atomicAdd.
// grid (12 colb, 32 j), 256 threads, kc=64.
// colb 0-7: qw; 8-9: kw; 10-11: vw.
__global__ __launch_bounds__(256) void k_qkv6(const float* __restrict__ qw,
                                              const float* __restrict__ kw,
                                              const float* __restrict__ vw,
                                              const float* __restrict__ xt,
                                              float* __restrict__ qkvacc) {
  int colb = blockIdx.x, j = blockIdx.y, t = threadIdx.x;
  const float* w; int ldw, col, outcol;
  if (colb < 8)        { w = qw; ldw = 2048; col = colb * 256 + t; outcol = col; }
  else if (colb < 10)  { w = kw; ldw = 512;  col = (colb - 8) * 256 + t;  outcol = 2048 + col; }
  else                 { w = vw; ldw = 512;  col = (colb - 10) * 256 + t; outcol = 2560 + col; }
  __shared__ __align__(16) float xs[64][32];
  int k0 = j * 64;
  for (int i2 = t; i2 < 64 * 32; i2 += 256)
    ((float*)xs)[i2] = xt[(size_t)k0 * 32 + i2];
  __syncthreads();
  float acc[32];
  #pragma unroll
  for (int r = 0; r < 32; r++) acc[r] = 0.f;
  const float* wp = w + (size_t)k0 * ldw + col;
  #pragma unroll 4
  for (int kk = 0; kk < 64; kk++) {
    float wv = wp[(size_t)kk * ldw];
    #pragma unroll
    for (int r4 = 0; r4 < 8; r4++) {
      float4 xr = *(const float4*)&xs[kk][r4 * 4];
      acc[r4*4+0] = fmaf(xr.x, wv, acc[r4*4+0]);
      acc[r4*4+1] = fmaf(xr.y, wv, acc[r4*4+1]);
      acc[r4*4+2] = fmaf(xr.z, wv, acc[r4*4+2]);
      acc[r4*4+3] = fmaf(xr.w, wv, acc[r4*4+3]);
    }
  }
  #pragma unroll
  for (int r = 0; r < 32; r++)
    atomicAdd(&qkvacc[(size_t)r * NQKV + outcol], acc[r]);
}

// ---------------- K2: fused single-pass flash attention, in-block merge.
// grid (NS, 32 b), 512 threads (8 waves), 3 blocks/CU (45KB LDS).
// wave = (w2 = pos group, half = head half); lane = hh2*16 + d4.
// Each w2 group streams K AND V for PW contiguous positions with online
// softmax; the 4 groups merge via LDS at the end -> ONE split per block.
__global__ __launch_bounds__(512, 6) void k_attn6(const float* __restrict__ ck,
                                                  const float* __restrict__ cv,
                                                  const float* __restrict__ qkvacc,
                                                  const float* __restrict__ rope,
                                                  __half* __restrict__ osplit,
                                                  float* __restrict__ msl,
                                                  const int* __restrict__ spp) {
  int s = blockIdx.x, b = blockIdx.y, tid = threadIdx.x;
  int sp = read_sp(spp);

  __shared__ __align__(16) float qs[8][4][64];
  __shared__ __align__(16) float knew[8][64];
  __shared__ __align__(16) float vnew[8][64];
  __shared__ __align__(16) float ml[4][32][2];
  __shared__ __align__(16) float ob[4][32][64];

  const float* qb = qkvacc + (size_t)b * NQKV;

  // stage q (RoPE, 1/8 folded), new k (RoPE), new v
  {
    int pi = tid * 2;
    #pragma unroll
    for (int u = 0; u < 2; u++, pi++) {       // 1024 q pairs
      int hq = pi >> 5, i = pi & 31;
      float cs = rope[2 * i], sn = rope[2 * i + 1];
      float a = qb[hq * 64 + 2 * i], bb = qb[hq * 64 + 2 * i + 1];
      qs[hq >> 2][hq & 3][2 * i]     = (a * cs - bb * sn) * 0.125f;
      qs[hq >> 2][hq & 3][2 * i + 1] = (a * sn + bb * cs) * 0.125f;
    }
    if (tid < 256) {                           // 256 k pairs
      int h = tid >> 5, i = tid & 31;
      float cs = rope[2 * i], sn = rope[2 * i + 1];
      float a = qb[2048 + h * 64 + 2 * i], bb = qb[2048 + h * 64 + 2 * i + 1];
      knew[h][2 * i]     = a * cs - bb * sn;
      knew[h][2 * i + 1] = a * sn + bb * cs;
    }
    { int h = tid >> 6, d = tid & 63; vnew[h][d] = qb[2560 + h * 64 + d]; }
  }
  __syncthreads();

  int w = tid >> 6, lane = tid & 63;
  int w2 = w >> 1, half = w & 1;
  int hh2 = lane >> 4, d4 = lane & 15;
  int h = half * 4 + hh2;

  float4 qv0 = *(const float4*)&qs[h][0][d4 * 4];
  float4 qv1 = *(const float4*)&qs[h][1][d4 * 4];
  float4 qv2 = *(const float4*)&qs[h][2][d4 * 4];
  float4 qv3 = *(const float4*)&qs[h][3][d4 * 4];
  float4 kn4 = *(const float4*)&knew[h][d4 * 4];
  float4 vn4 = *(const float4*)&vnew[h][d4 * 4];

  const float* kb = ck + (size_t)b * 2048 * 512 + half * 256 + lane * 4;
  const float* vb = cv + (size_t)b * 2048 * 512 + half * 256 + lane * 4;
  int p0 = s * SPL + w2 * PW;

  float m0 = -1e30f, m1 = -1e30f, m2 = -1e30f, m3 = -1e30f;
  float l0 = 0.f, l1 = 0.f, l2 = 0.f, l3 = 0.f;
  float4 o0 = {0,0,0,0}, o1 = {0,0,0,0}, o2 = {0,0,0,0}, o3 = {0,0,0,0};

  #pragma unroll 4
  for (int i = 0; i < PW; i++) {
    int p = p0 + i;
    float4 k4 = *(const float4*)(kb + (size_t)p * 512);
    float4 v4 = *(const float4*)(vb + (size_t)p * 512);
    if (p == sp) { k4 = kn4; v4 = vn4; }
    float s0 = qv0.x * k4.x + qv0.y * k4.y + qv0.z * k4.z + qv0.w * k4.w;
    float s1 = qv1.x * k4.x + qv1.y * k4.y + qv1.z * k4.z + qv1.w * k4.w;
    float s2 = qv2.x * k4.x + qv2.y * k4.y + qv2.z * k4.z + qv2.w * k4.w;
    float s3 = qv3.x * k4.x + qv3.y * k4.y + qv3.z * k4.z + qv3.w * k4.w;
    #pragma unroll
    for (int off = 1; off <= 8; off <<= 1) {   // reduce over d4 (16 lanes)
      s0 += __shfl_xor(s0, off);
      s1 += __shfl_xor(s1, off);
      s2 += __shfl_xor(s2, off);
      s3 += __shfl_xor(s3, off);
    }
    float mn0 = fmaxf(m0, s0), c0 = __expf(m0 - mn0), e0 = __expf(s0 - mn0);
    float mn1 = fmaxf(m1, s1), c1 = __expf(m1 - mn1), e1 = __expf(s1 - mn1);
    float mn2 = fmaxf(m2, s2), c2 = __expf(m2 - mn2), e2 = __expf(s2 - mn2);
    float mn3 = fmaxf(m3, s3), c3 = __expf(m3 - mn3), e3 = __expf(s3 - mn3);
    l0 = fmaf(l0, c0, e0); l1 = fmaf(l1, c1, e1);
    l2 = fmaf(l2, c2, e2); l3 = fmaf(l3, c3, e3);
    m0 = mn0; m1 = mn1; m2 = mn2; m3 = mn3;
    o0.x = fmaf(e0, v4.x, o0.x * c0); o0.y = fmaf(e0, v4.y, o0.y * c0);
    o0.z = fmaf(e0, v4.z, o0.z * c0); o0.w = fmaf(e0, v4.w, o0.w * c0);
    o1.x = fmaf(e1, v4.x, o1.x * c1); o1.y = fmaf(e1, v4.y, o1.y * c1);
    o1.z = fmaf(e1, v4.z, o1.z * c1); o1.w = fmaf(e1, v4.w, o1.w * c1);
    o2.x = fmaf(e2, v4.x, o2.x * c2); o2.y = fmaf(e2, v4.y, o2.y * c2);
    o2.z = fmaf(e2, v4.z, o2.z * c2); o2.w = fmaf(e2, v4.w, o2.w * c2);
    o3.x = fmaf(e3, v4.x, o3.x * c3); o3.y = fmaf(e3, v4.y, o3.y * c3);
    o3.z = fmaf(e3, v4.z, o3.z * c3); o3.w = fmaf(e3, v4.w, o3.w * c3);
  }

  // deposit this w2 group's (m, l, o) into LDS
  if (d4 == 0) {
    ml[w2][h * 4 + 0][0] = m0; ml[w2][h * 4 + 0][1] = l0;
    ml[w2][h * 4 + 1][0] = m1; ml[w2][h * 4 + 1][1] = l1;
    ml[w2][h * 4 + 2][0] = m2; ml[w2][h * 4 + 2][1] = l2;
    ml[w2][h * 4 + 3][0] = m3; ml[w2][h * 4 + 3][1] = l3;
  }
  *(float4*)&ob[w2][h * 4 + 0][d4 * 4] = o0;
  *(float4*)&ob[w2][h * 4 + 1][d4 * 4] = o1;
  *(float4*)&ob[w2][h * 4 + 2][d4 * 4] = o2;
  *(float4*)&ob[w2][h * 4 + 3][d4 * 4] = o3;
  __syncthreads();

  // merge the 4 w2 sub-splits -> one flash split per block
  for (int e = tid; e < 2048; e += 512) {
    int row = e >> 6, d = e & 63;
    float ma = fmaxf(fmaxf(ml[0][row][0], ml[1][row][0]),
                     fmaxf(ml[2][row][0], ml[3][row][0]));
    float w0 = __expf(ml[0][row][0] - ma), w1 = __expf(ml[1][row][0] - ma);
    float wq2 = __expf(ml[2][row][0] - ma), wq3 = __expf(ml[3][row][0] - ma);
    float L = w0 * ml[0][row][1] + w1 * ml[1][row][1] +
              wq2 * ml[2][row][1] + wq3 * ml[3][row][1];
    float o = w0 * ob[0][row][d] + w1 * ob[1][row][d] +
              wq2 * ob[2][row][d] + wq3 * ob[3][row][d];
    size_t rowi = ((size_t)b * NS + s) * 32 + row;
    osplit[rowi * 64 + d] = __float2half(o);
    if (d == 0) { msl[rowi * 2] = ma; msl[rowi * 2 + 1] = L; }
  }
}

// ---------------- K2b: flash combine over NS splits. grid (32 b, 4 g).
__global__ __launch_bounds__(256) void k_combine6(const __half* __restrict__ osplit,
                                                  const float* __restrict__ msl,
                                                  float* __restrict__ obt) {
  int b = blockIdx.x, g = blockIdx.y, t = threadIdx.x;
  int hq = g * 8 + (t >> 5);
  int d0 = (t & 31) * 2;
  float m = -1e30f;
  #pragma unroll 4
  for (int s4 = 0; s4 < NS; s4++)
    m = fmaxf(m, msl[(((size_t)b * NS + s4) * 32 + hq) * 2]);
  float L = 0.f, o0 = 0.f, o1 = 0.f;
  #pragma unroll 4
  for (int s4 = 0; s4 < NS; s4++) {
    size_t mi = (((size_t)b * NS + s4) * 32 + hq) * 2;
    float wgt = __expf(msl[mi] - m);
    L = fmaf(wgt, msl[mi + 1], L);
    const __half* op = osplit + (((size_t)b * NS + s4) * 32 + hq) * 64 + d0;
    o0 = fmaf(wgt, __half2float(op[0]), o0);
    o1 = fmaf(wgt, __half2float(op[1]), o1);
  }
  float invL = 1.f / L;
  obt[(size_t)(hq * 64 + d0) * 32 + b]     = o0 * invL;
  obt[(size_t)(hq * 64 + d0 + 1) * 32 + b] = o1 * invL;
}

// ---------------- K3: O GEMM, 1 col/thread, k-split via atomicAdd into out.
// grid (8 colb, 32 j), 256 threads, kc=64.
__global__ __launch_bounds__(256) void k_oproj6(const float* __restrict__ ow,
                                                const float* __restrict__ obt,
                                                float* __restrict__ out) {
  int colb = blockIdx.x, j = blockIdx.y, t = threadIdx.x;
  int col = colb * 256 + t;
  __shared__ __align__(16) float xs[64][32];
  int k0 = j * 64;
  for (int i2 = t; i2 < 64 * 32; i2 += 256)
    ((float*)xs)[i2] = obt[(size_t)k0 * 32 + i2];
  __syncthreads();
  float acc[32];
  #pragma unroll
  for (int r = 0; r < 32; r++) acc[r] = 0.f;
  const float* wp = ow + (size_t)k0 * 2048 + col;
  #pragma unroll 4
  for (int kk = 0; kk < 64; kk++) {
    float wv = wp[(size_t)kk * 2048];
    #pragma unroll
    for (int r4 = 0; r4 < 8; r4++) {
      float4 xr = *(const float4*)&xs[kk][r4 * 4];
      acc[r4*4+0] = fmaf(xr.x, wv, acc[r4*4+0]);
      acc[r4*4+1] = fmaf(xr.y, wv, acc[r4*4+1]);
      acc[r4*4+2] = fmaf(xr.z, wv, acc[r4*4+2]);
      acc[r4*4+3] = fmaf(xr.w, wv, acc[r4*4+3]);
    }
  }
  #pragma unroll
  for (int r = 0; r < 32; r++)
    atomicAdd(&out[(size_t)r * 2048 + col], acc[r]);
}

extern "C" void kernel_launch(void* const* d_in, const int* in_sizes, int n_in,
                              void* d_out, int out_size, void* d_ws, size_t ws_size,
                              hipStream_t stream) {
  const float* x  = (const float*)d_in[0];
  const float* qw = (const float*)d_in[1];
  const float* kw = (const float*)d_in[2];
  const float* vw = (const float*)d_in[3];
  const float* ow = (const float*)d_in[4];
  const float* ck = (const float*)d_in[5];
  const float* cv = (const float*)d_in[6];
  const int*   sp = (n_in >= 8) ? (const int*)d_in[7] : nullptr;

  // Fixed workspace layout (floats):
  // xt 65536 | qkvacc 98304 | obt 65536 | msl 65536 | rope 64 | osplit 2M halves
  float* ws     = (float*)d_ws;
  float* xt     = ws;                         // 65536
  float* qkvacc = xt + 65536;                 // 98304
  float* obt    = qkvacc + 98304;             // 65536
  float* msl    = obt + 65536;                // 32*NS*32*2 = 65536
  float* rope   = msl + 65536;                // 64
  __half* osplit = (__half*)(rope + 64);      // 32*NS*32*64 = 2097152 halves
  float* out    = (float*)d_out;

  k_prep6   <<<256,          256, 0, stream>>>(x, xt, qkvacc, out, rope, sp);
  k_qkv6    <<<dim3(12, 32), 256, 0, stream>>>(qw, kw, vw, xt, qkvacc);
  k_attn6   <<<dim3(NS, 32), 512, 0, stream>>>(ck, cv, qkvacc, rope, osplit, msl, sp);
  k_combine6<<<dim3(32, 4),  256, 0, stream>>>(osplit, msl, obt);
  k_oproj6  <<<dim3(8, 32),  256, 0, stream>>>(ow, obt, out);
}

// Round 7
// 368.936 us; speedup vs baseline: 1.1453x; 1.1453x over previous
//
#include <hip/hip_runtime.h>
#include <hip/hip_fp16.h>
#include <math.h>

// B=32, S=1, DIM=2048, NH=32, NKV=8, HD=64, L=2048, START_POS=2047.
// Inputs float32. OUTPUT float32.
#define NQKV 3072
#define NS   32     // flash splits per batch (block level)
#define SPL  64     // positions per block split
#define PW   16     // positions per w2 wave-group (SPL/4)

__device__ __forceinline__ int read_sp(const int* spp) {
  if (!spp) return 2047;
  int raw = spp[0];
  if (raw >= 0 && raw < 2048) return raw;
  union { int i; float f; } u; u.i = raw;
  if (u.f >= 0.f && u.f < 2048.f) return (int)u.f;
  return 2047;
}

// ---------------- K0: transpose x -> xt[2048][32], zero qkvacc + out,
//                  block 0 computes RoPE cos/sin table (f64 angles)
__global__ __launch_bounds__(256) void k_prep7(const float* __restrict__ x,
                                               float* __restrict__ xt,
                                               float* __restrict__ qkvacc,
                                               float* __restrict__ out,
                                               float* __restrict__ rope,
                                               const int* __restrict__ spp) {
  int idx = blockIdx.x * 256 + threadIdx.x;   // 65536 total
  int r = idx >> 11, k = idx & 2047;
  xt[k * 32 + r] = x[idx];
  out[idx] = 0.f;                              // 65536 = 32*2048
  for (int z = idx; z < 32 * NQKV; z += 65536) qkvacc[z] = 0.f;
  if (blockIdx.x == 0 && threadIdx.x < 32) {
    int i = threadIdx.x;
    int sp = read_sp(spp);
    double freq = pow(10000.0, -(double)(2 * i) / 64.0);
    double ang = (double)sp * freq;
    double sd, cd; sincos(ang, &sd, &cd);
    rope[2 * i]     = (float)cd;
    rope[2 * i + 1] = (float)sd;
  }
}

// ---------------- K1: QKV GEMM, 1 col/thread, k-split via atomicAdd.
// grid (12 colb, 32 j), 256 threads, kc=64.
// colb 0-7: qw; 8-9: kw; 10-11: vw.
__global__ __launch_bounds__(256) void k_qkv7(const float* __restrict__ qw,
                                              const float* __restrict__ kw,
                                              const float* __restrict__ vw,
                                              const float* __restrict__ xt,
                                              float* __restrict__ qkvacc) {
  int colb = blockIdx.x, j = blockIdx.y, t = threadIdx.x;
  const float* w; int ldw, col, outcol;
  if (colb < 8)        { w = qw; ldw = 2048; col = colb * 256 + t; outcol = col; }
  else if (colb < 10)  { w = kw; ldw = 512;  col = (colb - 8) * 256 + t;  outcol = 2048 + col; }
  else                 { w = vw; ldw = 512;  col = (colb - 10) * 256 + t; outcol = 2560 + col; }
  __shared__ __align__(16) float xs[64][32];
  int k0 = j * 64;
  for (int i2 = t; i2 < 64 * 32; i2 += 256)
    ((float*)xs)[i2] = xt[(size_t)k0 * 32 + i2];
  __syncthreads();
  float acc[32];
  #pragma unroll
  for (int r = 0; r < 32; r++) acc[r] = 0.f;
  const float* wp = w + (size_t)k0 * ldw + col;
  #pragma unroll 4
  for (int kk = 0; kk < 64; kk++) {
    float wv = wp[(size_t)kk * ldw];
    #pragma unroll
    for (int r4 = 0; r4 < 8; r4++) {
      float4 xr = *(const float4*)&xs[kk][r4 * 4];
      acc[r4*4+0] = fmaf(xr.x, wv, acc[r4*4+0]);
      acc[r4*4+1] = fmaf(xr.y, wv, acc[r4*4+1]);
      acc[r4*4+2] = fmaf(xr.z, wv, acc[r4*4+2]);
      acc[r4*4+3] = fmaf(xr.w, wv, acc[r4*4+3]);
    }
  }
  #pragma unroll
  for (int r = 0; r < 32; r++)
    atomicAdd(&qkvacc[(size_t)r * NQKV + outcol], acc[r]);
}

// ---------------- K2: fused single-pass flash attention, in-block merge.
// grid (NS, 32 b) = 1024 blocks, 512 threads (8 waves), 4 blocks/CU.
// wave = (w2 = pos group, half = head half); lane = hh2*16 + d4.
// Each w2 group streams K AND V for PW contiguous positions with online
// softmax; the 4 groups merge via LDS (f16) at the end -> ONE split/block.
__global__ __launch_bounds__(512, 4) void k_attn7(const float* __restrict__ ck,
                                                  const float* __restrict__ cv,
                                                  const float* __restrict__ qkvacc,
                                                  const float* __restrict__ rope,
                                                  __half* __restrict__ osplit,
                                                  float* __restrict__ msl,
                                                  const int* __restrict__ spp) {
  int s = blockIdx.x, b = blockIdx.y, tid = threadIdx.x;
  int sp = read_sp(spp);

  __shared__ __align__(16) float qs[8][4][64];
  __shared__ __align__(16) float knew[8][64];
  __shared__ __align__(16) float vnew[8][64];
  __shared__ __align__(16) float ml[4][32][2];
  __shared__ __align__(16) __half2 ob2[4][32][33];   // +1 pad: conflict-free

  const float* qb = qkvacc + (size_t)b * NQKV;

  // stage q (RoPE, 1/8 folded), new k (RoPE), new v
  {
    int pi = tid * 2;
    #pragma unroll
    for (int u = 0; u < 2; u++, pi++) {       // 1024 q pairs
      int hq = pi >> 5, i = pi & 31;
      float cs = rope[2 * i], sn = rope[2 * i + 1];
      float a = qb[hq * 64 + 2 * i], bb = qb[hq * 64 + 2 * i + 1];
      qs[hq >> 2][hq & 3][2 * i]     = (a * cs - bb * sn) * 0.125f;
      qs[hq >> 2][hq & 3][2 * i + 1] = (a * sn + bb * cs) * 0.125f;
    }
    if (tid < 256) {                           // 256 k pairs
      int h = tid >> 5, i = tid & 31;
      float cs = rope[2 * i], sn = rope[2 * i + 1];
      float a = qb[2048 + h * 64 + 2 * i], bb = qb[2048 + h * 64 + 2 * i + 1];
      knew[h][2 * i]     = a * cs - bb * sn;
      knew[h][2 * i + 1] = a * sn + bb * cs;
    }
    { int h = tid >> 6, d = tid & 63; vnew[h][d] = qb[2560 + h * 64 + d]; }
  }
  __syncthreads();

  int w = tid >> 6, lane = tid & 63;
  int w2 = w >> 1, half = w & 1;
  int hh2 = lane >> 4, d4 = lane & 15;
  int h = half * 4 + hh2;

  float4 qv0 = *(const float4*)&qs[h][0][d4 * 4];
  float4 qv1 = *(const float4*)&qs[h][1][d4 * 4];
  float4 qv2 = *(const float4*)&qs[h][2][d4 * 4];
  float4 qv3 = *(const float4*)&qs[h][3][d4 * 4];
  float4 kn4 = *(const float4*)&knew[h][d4 * 4];
  float4 vn4 = *(const float4*)&vnew[h][d4 * 4];

  const float* kb = ck + (size_t)b * 2048 * 512 + half * 256 + lane * 4;
  const float* vb = cv + (size_t)b * 2048 * 512 + half * 256 + lane * 4;
  int p0 = s * SPL + w2 * PW;

  float m0 = -1e30f, m1 = -1e30f, m2 = -1e30f, m3 = -1e30f;
  float l0 = 0.f, l1 = 0.f, l2 = 0.f, l3 = 0.f;
  float4 o0 = {0,0,0,0}, o1 = {0,0,0,0}, o2 = {0,0,0,0}, o3 = {0,0,0,0};

  #pragma unroll 4
  for (int i = 0; i < PW; i++) {
    int p = p0 + i;
    float4 k4 = *(const float4*)(kb + (size_t)p * 512);
    float4 v4 = *(const float4*)(vb + (size_t)p * 512);
    if (p == sp) { k4 = kn4; v4 = vn4; }
    float s0 = qv0.x * k4.x + qv0.y * k4.y + qv0.z * k4.z + qv0.w * k4.w;
    float s1 = qv1.x * k4.x + qv1.y * k4.y + qv1.z * k4.z + qv1.w * k4.w;
    float s2 = qv2.x * k4.x + qv2.y * k4.y + qv2.z * k4.z + qv2.w * k4.w;
    float s3 = qv3.x * k4.x + qv3.y * k4.y + qv3.z * k4.z + qv3.w * k4.w;
    #pragma unroll
    for (int off = 1; off <= 8; off <<= 1) {   // reduce over d4 (16 lanes)
      s0 += __shfl_xor(s0, off);
      s1 += __shfl_xor(s1, off);
      s2 += __shfl_xor(s2, off);
      s3 += __shfl_xor(s3, off);
    }
    float mn0 = fmaxf(m0, s0), c0 = __expf(m0 - mn0), e0 = __expf(s0 - mn0);
    float mn1 = fmaxf(m1, s1), c1 = __expf(m1 - mn1), e1 = __expf(s1 - mn1);
    float mn2 = fmaxf(m2, s2), c2 = __expf(m2 - mn2), e2 = __expf(s2 - mn2);
    float mn3 = fmaxf(m3, s3), c3 = __expf(m3 - mn3), e3 = __expf(s3 - mn3);
    l0 = fmaf(l0, c0, e0); l1 = fmaf(l1, c1, e1);
    l2 = fmaf(l2, c2, e2); l3 = fmaf(l3, c3, e3);
    m0 = mn0; m1 = mn1; m2 = mn2; m3 = mn3;
    o0.x = fmaf(e0, v4.x, o0.x * c0); o0.y = fmaf(e0, v4.y, o0.y * c0);
    o0.z = fmaf(e0, v4.z, o0.z * c0); o0.w = fmaf(e0, v4.w, o0.w * c0);
    o1.x = fmaf(e1, v4.x, o1.x * c1); o1.y = fmaf(e1, v4.y, o1.y * c1);
    o1.z = fmaf(e1, v4.z, o1.z * c1); o1.w = fmaf(e1, v4.w, o1.w * c1);
    o2.x = fmaf(e2, v4.x, o2.x * c2); o2.y = fmaf(e2, v4.y, o2.y * c2);
    o2.z = fmaf(e2, v4.z, o2.z * c2); o2.w = fmaf(e2, v4.w, o2.w * c2);
    o3.x = fmaf(e3, v4.x, o3.x * c3); o3.y = fmaf(e3, v4.y, o3.y * c3);
    o3.z = fmaf(e3, v4.z, o3.z * c3); o3.w = fmaf(e3, v4.w, o3.w * c3);
  }

  // deposit this w2 group's (m, l, o->f16) into LDS
  if (d4 == 0) {
    ml[w2][h * 4 + 0][0] = m0; ml[w2][h * 4 + 0][1] = l0;
    ml[w2][h * 4 + 1][0] = m1; ml[w2][h * 4 + 1][1] = l1;
    ml[w2][h * 4 + 2][0] = m2; ml[w2][h * 4 + 2][1] = l2;
    ml[w2][h * 4 + 3][0] = m3; ml[w2][h * 4 + 3][1] = l3;
  }
  ob2[w2][h * 4 + 0][d4 * 2]     = __floats2half2_rn(o0.x, o0.y);
  ob2[w2][h * 4 + 0][d4 * 2 + 1] = __floats2half2_rn(o0.z, o0.w);
  ob2[w2][h * 4 + 1][d4 * 2]     = __floats2half2_rn(o1.x, o1.y);
  ob2[w2][h * 4 + 1][d4 * 2 + 1] = __floats2half2_rn(o1.z, o1.w);
  ob2[w2][h * 4 + 2][d4 * 2]     = __floats2half2_rn(o2.x, o2.y);
  ob2[w2][h * 4 + 2][d4 * 2 + 1] = __floats2half2_rn(o2.z, o2.w);
  ob2[w2][h * 4 + 3][d4 * 2]     = __floats2half2_rn(o3.x, o3.y);
  ob2[w2][h * 4 + 3][d4 * 2 + 1] = __floats2half2_rn(o3.z, o3.w);
  __syncthreads();

  // merge the 4 w2 sub-splits -> one flash split per block (1024 half2 elems)
  for (int e = tid; e < 1024; e += 512) {
    int row = e >> 5, d2 = e & 31;
    float ma = fmaxf(fmaxf(ml[0][row][0], ml[1][row][0]),
                     fmaxf(ml[2][row][0], ml[3][row][0]));
    float w0 = __expf(ml[0][row][0] - ma), w1 = __expf(ml[1][row][0] - ma);
    float g2 = __expf(ml[2][row][0] - ma), g3 = __expf(ml[3][row][0] - ma);
    float L = w0 * ml[0][row][1] + w1 * ml[1][row][1] +
              g2 * ml[2][row][1] + g3 * ml[3][row][1];
    float2 a = __half22float2(ob2[0][row][d2]);
    float2 bq = __half22float2(ob2[1][row][d2]);
    float2 c = __half22float2(ob2[2][row][d2]);
    float2 dd = __half22float2(ob2[3][row][d2]);
    float olo = w0 * a.x + w1 * bq.x + g2 * c.x + g3 * dd.x;
    float ohi = w0 * a.y + w1 * bq.y + g2 * c.y + g3 * dd.y;
    size_t rowi = ((size_t)b * NS + s) * 32 + row;
    *(__half2*)&osplit[rowi * 64 + d2 * 2] = __floats2half2_rn(olo, ohi);
    if (d2 == 0) { msl[rowi * 2] = ma; msl[rowi * 2 + 1] = L; }
  }
}

// ---------------- K2b: flash combine over NS splits. grid (32 b, 4 g).
__global__ __launch_bounds__(256) void k_combine7(const __half* __restrict__ osplit,
                                                  const float* __restrict__ msl,
                                                  float* __restrict__ obt) {
  int b = blockIdx.x, g = blockIdx.y, t = threadIdx.x;
  int hq = g * 8 + (t >> 5);
  int d0 = (t & 31) * 2;
  float m = -1e30f;
  #pragma unroll 4
  for (int s4 = 0; s4 < NS; s4++)
    m = fmaxf(m, msl[(((size_t)b * NS + s4) * 32 + hq) * 2]);
  float L = 0.f, o0 = 0.f, o1 = 0.f;
  #pragma unroll 4
  for (int s4 = 0; s4 < NS; s4++) {
    size_t mi = (((size_t)b * NS + s4) * 32 + hq) * 2;
    float wgt = __expf(msl[mi] - m);
    L = fmaf(wgt, msl[mi + 1], L);
    const __half* op = osplit + (((size_t)b * NS + s4) * 32 + hq) * 64 + d0;
    o0 = fmaf(wgt, __half2float(op[0]), o0);
    o1 = fmaf(wgt, __half2float(op[1]), o1);
  }
  float invL = 1.f / L;
  obt[(size_t)(hq * 64 + d0) * 32 + b]     = o0 * invL;
  obt[(size_t)(hq * 64 + d0 + 1) * 32 + b] = o1 * invL;
}

// ---------------- K3: O GEMM, 1 col/thread, k-split via atomicAdd into out.
// grid (8 colb, 32 j), 256 threads, kc=64.
__global__ __launch_bounds__(256) void k_oproj7(const float* __restrict__ ow,
                                                const float* __restrict__ obt,
                                                float* __restrict__ out) {
  int colb = blockIdx.x, j = blockIdx.y, t = threadIdx.x;
  int col = colb * 256 + t;
  __shared__ __align__(16) float xs[64][32];
  int k0 = j * 64;
  for (int i2 = t; i2 < 64 * 32; i2 += 256)
    ((float*)xs)[i2] = obt[(size_t)k0 * 32 + i2];
  __syncthreads();
  float acc[32];
  #pragma unroll
  for (int r = 0; r < 32; r++) acc[r] = 0.f;
  const float* wp = ow + (size_t)k0 * 2048 + col;
  #pragma unroll 4
  for (int kk = 0; kk < 64; kk++) {
    float wv = wp[(size_t)kk * 2048];
    #pragma unroll
    for (int r4 = 0; r4 < 8; r4++) {
      float4 xr = *(const float4*)&xs[kk][r4 * 4];
      acc[r4*4+0] = fmaf(xr.x, wv, acc[r4*4+0]);
      acc[r4*4+1] = fmaf(xr.y, wv, acc[r4*4+1]);
      acc[r4*4+2] = fmaf(xr.z, wv, acc[r4*4+2]);
      acc[r4*4+3] = fmaf(xr.w, wv, acc[r4*4+3]);
    }
  }
  #pragma unroll
  for (int r = 0; r < 32; r++)
    atomicAdd(&out[(size_t)r * 2048 + col], acc[r]);
}

extern "C" void kernel_launch(void* const* d_in, const int* in_sizes, int n_in,
                              void* d_out, int out_size, void* d_ws, size_t ws_size,
                              hipStream_t stream) {
  const float* x  = (const float*)d_in[0];
  const float* qw = (const float*)d_in[1];
  const float* kw = (const float*)d_in[2];
  const float* vw = (const float*)d_in[3];
  const float* ow = (const float*)d_in[4];
  const float* ck = (const float*)d_in[5];
  const float* cv = (const float*)d_in[6];
  const int*   sp = (n_in >= 8) ? (const int*)d_in[7] : nullptr;

  // Fixed workspace layout (floats):
  // xt 65536 | qkvacc 98304 | obt 65536 | msl 65536 | rope 64 | osplit 2M halves
  float* ws     = (float*)d_ws;
  float* xt     = ws;                         // 65536
  float* qkvacc = xt + 65536;                 // 98304
  float* obt    = qkvacc + 98304;             // 65536
  float* msl    = obt + 65536;                // 32*NS*32*2 = 65536
  float* rope   = msl + 65536;                // 64
  __half* osplit = (__half*)(rope + 64);      // 32*NS*32*64 = 2097152 halves
  float* out    = (float*)d_out;

  k_prep7   <<<256,          256, 0, stream>>>(x, xt, qkvacc, out, rope, sp);
  k_qkv7    <<<dim3(12, 32), 256, 0, stream>>>(qw, kw, vw, xt, qkvacc);
  k_attn7   <<<dim3(NS, 32), 512, 0, stream>>>(ck, cv, qkvacc, rope, osplit, msl, sp);
  k_combine7<<<dim3(32, 4),  256, 0, stream>>>(osplit, msl, obt);
  k_oproj7  <<<dim3(8, 32),  256, 0, stream>>>(ow, obt, out);
}